// Round 7
// baseline (196.511 us; speedup 1.0000x reference)
//
#include <hip/hip_runtime.h>
#include <stdint.h>

// BertSelfAttentionWithRelation  B=4 L=512 H=12 D=64 HIDDEN=768
// Round 7: fix the relv ACCESS PATTERN (the invariant bottleneck, 1.6 TB/s
// across all prior rounds: 256B reads at 128KB stride).
//   k_relA: relk MFMA scores + softmax -> pbf (relk contiguous per block;
//           2-slot counted-vmcnt pipeline, ~60 VGPR -> no spill)
//   k_relv: NEW decomposition block=(b, r-chunk 128, l-chunk 16): relv read
//           in 4KB contiguous chunks; P staged in LDS (48KB bf16 swizzled);
//           writes 4 r-chunk partials (overlaid on dead S region)
//   k_pv:   PV MFMA + sum of 4 partials -> out
//   ws: hb 0 | wt 3.1M | qbf 6.7M | kbf 9.8M | vbt 13.0M | S/part 16.1M |
//       pbf 66.5M | (crel region unused)

typedef __attribute__((ext_vector_type(8))) short bf16x8;
typedef __attribute__((ext_vector_type(4))) float f32x4;
typedef __attribute__((ext_vector_type(4))) unsigned int u32x4;

__device__ __forceinline__ unsigned short f2bf(float f) {
  union { float f; unsigned int u; } v; v.f = f;
  unsigned int r = v.u + 0x7fffu + ((v.u >> 16) & 1u);
  return (unsigned short)(r >> 16);
}
__device__ __forceinline__ float bf2f(unsigned short s) {
  union { unsigned int u; float f; } v; v.u = ((unsigned int)s) << 16;
  return v.f;
}
__device__ __forceinline__ void lds_barrier() {
  asm volatile("s_waitcnt lgkmcnt(0)\ns_barrier" ::: "memory");
}
__device__ __forceinline__ unsigned cvtpk(float lo, float hi) {
  unsigned r;
  asm("v_cvt_pk_bf16_f32 %0, %1, %2" : "=v"(r) : "v"(lo), "v"(hi));
  return r;
}

#define GL16(dst, addr, OFF)                                                  \
  asm volatile("global_load_dwordx4 %0, %1, off offset:" #OFF                \
               : "=v"(dst) : "v"(addr))
#define WAITV(N)                                                              \
  do {                                                                        \
    asm volatile("s_waitcnt vmcnt(" #N ")" ::: "memory");                     \
    __builtin_amdgcn_sched_barrier(0);                                        \
  } while (0)

// ---------------- K0a: hidden fp32 -> bf16 ----------------
__global__ void k_cvt_hidden(const float* __restrict__ x, unsigned short* __restrict__ y) {
  int i = blockIdx.x * 256 + threadIdx.x;
  float4 v = reinterpret_cast<const float4*>(x)[i];
  ushort4 o;
  o.x = f2bf(v.x); o.y = f2bf(v.y); o.z = f2bf(v.z); o.w = f2bf(v.w);
  reinterpret_cast<ushort4*>(y)[i] = o;
}

// ---------------- K0b: W -> W^T concat bf16 ----------------
__global__ void k_transp_w(const float* __restrict__ Wq, const float* __restrict__ Wk,
                           const float* __restrict__ Wv, unsigned short* __restrict__ wt) {
  __shared__ float t[64][65];
  const int kt = blockIdx.x, nt = blockIdx.y, wsel = blockIdx.z;
  const float* W = wsel == 0 ? Wq : (wsel == 1 ? Wk : Wv);
  const int lx = threadIdx.x & 63, ly = threadIdx.x >> 6;
  for (int i = 0; i < 64; i += 4)
    t[ly + i][lx] = W[(size_t)(kt * 64 + ly + i) * 768 + nt * 64 + lx];
  __syncthreads();
  for (int i = 0; i < 64; i += 4) {
    int r = ly + i;
    wt[((size_t)wsel * 768 + nt * 64 + r) * 768 + kt * 64 + lx] = f2bf(t[lx][r]);
  }
}

// ---------------- K1: fused QKV GEMM (bf16 MFMA) ----------------
__global__ __launch_bounds__(256) void k_qkv_gemm(
    const unsigned short* __restrict__ A, const unsigned short* __restrict__ Bt,
    const float* __restrict__ bq, const float* __restrict__ bk, const float* __restrict__ bv,
    unsigned short* __restrict__ qbf, unsigned short* __restrict__ kbf,
    unsigned short* __restrict__ vbt) {
  __shared__ __align__(16) unsigned short lA[64 * 64];
  __shared__ __align__(16) unsigned short lB[64 * 64];
  const int tid = threadIdx.x, lane = tid & 63, w = tid >> 6;
  const int m0 = blockIdx.x * 64, n0 = blockIdx.y * 64;
  const int wm = (w >> 1) * 32, wn = (w & 1) * 32;
  f32x4 acc[2][2] = {};

  for (int kt = 0; kt < 12; ++kt) {
    __syncthreads();
#pragma unroll
    for (int i = 0; i < 2; ++i) {
      int e16 = i * 256 + tid;
      int row = e16 >> 3;
      int kb = (e16 & 7) * 16;
      int dst = row * 128 + (kb ^ ((row & 7) << 4));
      u32x4 va = *(const u32x4*)((const char*)A + (size_t)(m0 + row) * 1536 + kt * 128 + kb);
      *(u32x4*)((char*)lA + dst) = va;
      u32x4 vb = *(const u32x4*)((const char*)Bt + (size_t)(n0 + row) * 1536 + kt * 128 + kb);
      *(u32x4*)((char*)lB + dst) = vb;
    }
    __syncthreads();
#pragma unroll
    for (int ks = 0; ks < 2; ++ks) {
      bf16x8 fa[2], fb[2];
      const int kbyte = (ks * 32 + (lane >> 4) * 8) * 2;
#pragma unroll
      for (int mi = 0; mi < 2; ++mi) {
        int row = wm + mi * 16 + (lane & 15);
        fa[mi] = *(const bf16x8*)((const char*)lA + row * 128 + (kbyte ^ ((row & 7) << 4)));
      }
#pragma unroll
      for (int ni = 0; ni < 2; ++ni) {
        int row = wn + ni * 16 + (lane & 15);
        fb[ni] = *(const bf16x8*)((const char*)lB + row * 128 + (kbyte ^ ((row & 7) << 4)));
      }
#pragma unroll
      for (int mi = 0; mi < 2; ++mi)
#pragma unroll
        for (int ni = 0; ni < 2; ++ni)
          acc[mi][ni] = __builtin_amdgcn_mfma_f32_16x16x32_bf16(fa[mi], fb[ni], acc[mi][ni], 0, 0, 0);
    }
  }
#pragma unroll
  for (int mi = 0; mi < 2; ++mi)
#pragma unroll
    for (int ni = 0; ni < 2; ++ni) {
      int gn = n0 + wn + ni * 16 + (lane & 15);
      float bias = (gn < 768) ? bq[gn] : (gn < 1536 ? bk[gn - 768] : bv[gn - 1536]);
#pragma unroll
      for (int r = 0; r < 4; ++r) {
        int gm = m0 + wm + mi * 16 + ((lane >> 4) << 2) + r;
        float val = acc[mi][ni][r] + bias;
        int b = gm >> 9, l = gm & 511;
        int d = gn & 63;
        if (gn < 768) {
          int h = gn >> 6;
          qbf[(((size_t)(b * 12 + h)) * 512 + l) * 64 + d] = f2bf(val);
        } else if (gn < 1536) {
          int h = (gn - 768) >> 6;
          kbf[(((size_t)(b * 12 + h)) * 512 + l) * 64 + d] = f2bf(val);
        } else {
          int h = (gn - 1536) >> 6;
          vbt[(((size_t)(b * 12 + h)) * 64 + d) * 512 + l] = f2bf(val);
        }
      }
    }
}

// ---------------- K2a: content scores S = q.k^T per (b,h) ----------------
__global__ __launch_bounds__(256) void k_scores(
    const unsigned short* __restrict__ qbf, const unsigned short* __restrict__ kbf,
    float* __restrict__ S) {
  __shared__ __align__(16) unsigned short lQ[64 * 64];
  __shared__ __align__(16) unsigned short lK[64 * 64];
  const int tid = threadIdx.x, lane = tid & 63, w = tid >> 6;
  const int mt = blockIdx.x, lt = blockIdx.y, bh = blockIdx.z;
  const int wm = (w >> 1) * 32, wn = (w & 1) * 32;
  f32x4 acc[2][2] = {};
#pragma unroll
  for (int i = 0; i < 2; ++i) {
    int e16 = i * 256 + tid;
    int row = e16 >> 3;
    int kb = (e16 & 7) * 16;
    int dst = row * 128 + (kb ^ ((row & 7) << 4));
    u32x4 vq = *(const u32x4*)((const char*)qbf + ((size_t)bh * 512 + lt * 64 + row) * 128 + kb);
    *(u32x4*)((char*)lQ + dst) = vq;
    u32x4 vk = *(const u32x4*)((const char*)kbf + ((size_t)bh * 512 + mt * 64 + row) * 128 + kb);
    *(u32x4*)((char*)lK + dst) = vk;
  }
  __syncthreads();
#pragma unroll
  for (int ks = 0; ks < 2; ++ks) {
    bf16x8 fa[2], fb[2];
    const int kbyte = (ks * 32 + (lane >> 4) * 8) * 2;
#pragma unroll
    for (int mi = 0; mi < 2; ++mi) {
      int row = wm + mi * 16 + (lane & 15);
      fa[mi] = *(const bf16x8*)((const char*)lQ + row * 128 + (kbyte ^ ((row & 7) << 4)));
    }
#pragma unroll
    for (int ni = 0; ni < 2; ++ni) {
      int row = wn + ni * 16 + (lane & 15);
      fb[ni] = *(const bf16x8*)((const char*)lK + row * 128 + (kbyte ^ ((row & 7) << 4)));
    }
#pragma unroll
    for (int mi = 0; mi < 2; ++mi)
#pragma unroll
      for (int ni = 0; ni < 2; ++ni)
        acc[mi][ni] = __builtin_amdgcn_mfma_f32_16x16x32_bf16(fa[mi], fb[ni], acc[mi][ni], 0, 0, 0);
  }
#pragma unroll
  for (int mi = 0; mi < 2; ++mi)
#pragma unroll
    for (int ni = 0; ni < 2; ++ni) {
      int gm = mt * 64 + wn + ni * 16 + (lane & 15);
#pragma unroll
      for (int r = 0; r < 4; ++r) {
        int gl = lt * 64 + wm + mi * 16 + ((lane >> 4) << 2) + r;
        S[(size_t)bh * 262144 + (size_t)gl * 512 + gm] = acc[mi][ni][r];
      }
    }
}

// ---------------- K2b: rel-K scores + softmax -> pbf, one block per (b,l) --
__global__ __launch_bounds__(256) void k_relA(
    const unsigned short* __restrict__ qbf,
    const float* __restrict__ relk,   // [B][L][L][D]  (b, l, r, d)
    const float* __restrict__ S,
    unsigned short* __restrict__ pbf) {
  __shared__ __align__(16) char X[24576];   // S_rel [12][512] f32 swizzled
  const int tid = threadIdx.x, lane = tid & 63, w = tid >> 6;
  const int bl = blockIdx.x, b = bl >> 9, l = bl & 511;
  const int lm = lane & 15, lg = lane >> 4;
  const int hq = lm < 12 ? lm : 11;

  union { f32x4 f; bf16x8 b; } qa0, qa1;
  const char* aQ = (const char*)qbf + (((size_t)b * 12 + hq) * 512 + l) * 128 + (size_t)lg * 16;
  GL16(qa0.f, aQ, 0);
  GL16(qa1.f, aQ, 64);

  const char* aA = (const char*)relk + (size_t)bl * 131072 +
                   (size_t)(w * 128 + lm) * 256 + (size_t)lg * 32;
  f32x4 td[2][4];
#define TISSUE(t, s)                                                          \
  do {                                                                        \
    const char* p_ = aA + (size_t)(t) * 4096;                                 \
    GL16(td[s][0], p_, 0);   GL16(td[s][1], p_, 16);                          \
    GL16(td[s][2], p_, 128); GL16(td[s][3], p_, 144);                         \
  } while (0)
#define ACONSUME(t, s)                                                        \
  do {                                                                        \
    union { bf16x8 v; unsigned u[4]; } fb0, fb1;                              \
    fb0.u[0] = cvtpk(td[s][0][0], td[s][0][1]);                               \
    fb0.u[1] = cvtpk(td[s][0][2], td[s][0][3]);                               \
    fb0.u[2] = cvtpk(td[s][1][0], td[s][1][1]);                               \
    fb0.u[3] = cvtpk(td[s][1][2], td[s][1][3]);                               \
    fb1.u[0] = cvtpk(td[s][2][0], td[s][2][1]);                               \
    fb1.u[1] = cvtpk(td[s][2][2], td[s][2][3]);                               \
    fb1.u[2] = cvtpk(td[s][3][0], td[s][3][1]);                               \
    fb1.u[3] = cvtpk(td[s][3][2], td[s][3][3]);                               \
    f32x4 acc = {0.f, 0.f, 0.f, 0.f};                                         \
    acc = __builtin_amdgcn_mfma_f32_16x16x32_bf16(qa0.b, fb0.v, acc, 0, 0, 0);\
    acc = __builtin_amdgcn_mfma_f32_16x16x32_bf16(qa1.b, fb1.v, acc, 0, 0, 0);\
    if (lg < 3) {                                                             \
      const int r_ = w * 128 + (t) * 16 + lm;                                 \
      _Pragma("unroll")                                                       \
      for (int reg = 0; reg < 4; ++reg)                                       \
        *(float*)(X + (lg * 4 + reg) * 2048 + ((r_ * 4) ^ (lg << 6))) =       \
            acc[reg];                                                         \
    }                                                                         \
  } while (0)

  TISSUE(0, 0); TISSUE(1, 1);
  WAITV(4); ACONSUME(0, 0); TISSUE(2, 0);
  WAITV(4); ACONSUME(1, 1); TISSUE(3, 1);
  WAITV(4); ACONSUME(2, 0); TISSUE(4, 0);
  WAITV(4); ACONSUME(3, 1); TISSUE(5, 1);
  WAITV(4); ACONSUME(4, 0); TISSUE(6, 0);
  WAITV(4); ACONSUME(5, 1); TISSUE(7, 1);
  WAITV(4); ACONSUME(6, 0);
  WAITV(0); ACONSUME(7, 1);
#undef TISSUE
#undef ACONSUME

  lds_barrier();   // S_rel visible

  // softmax; wave owns h = 3w..3w+2; content S loaded inline
#pragma unroll
  for (int hh = 0; hh < 3; ++hh) {
    const int h = w * 3 + hh;
    const int sw = ((h >> 2) & 3) << 6;
    const size_t srow = (((size_t)b * 12 + h) * 512 + l) * 512;
    const float* sp = S + srow + lane;
    float sv[8];
    float mx = -1e30f;
#pragma unroll
    for (int j = 0; j < 8; ++j) {
      const int r = j * 64 + lane;
      float s = (*(const float*)(X + h * 2048 + ((r * 4) ^ sw)) + sp[j * 64]) * 0.125f;
      sv[j] = s;
      mx = fmaxf(mx, s);
    }
#pragma unroll
    for (int off = 32; off; off >>= 1) mx = fmaxf(mx, __shfl_xor(mx, off));
    float sm = 0.f;
#pragma unroll
    for (int j = 0; j < 8; ++j) { sv[j] = __expf(sv[j] - mx); sm += sv[j]; }
#pragma unroll
    for (int off = 32; off; off >>= 1) sm += __shfl_xor(sm, off);
    const float inv = 1.f / sm;
#pragma unroll
    for (int j = 0; j < 8; ++j)
      pbf[srow + j * 64 + lane] = f2bf(sv[j] * inv);
  }
}

// ---------------- K2c: rel-V context, contiguous streaming ----------------
// block = (lg, rc, b): r in [rc*128, +128), l in [lg*16, +16)
// wave owns 4 l's; lane: l = l0 + w*4 + (lane>>4), d-quad = (lane&15)*4
__global__ __launch_bounds__(256) void k_relv(
    const unsigned short* __restrict__ pbf,   // [B][H][L][R] bf16
    const float* __restrict__ relv,           // [B][R][L][D] f32
    float* __restrict__ part) {               // [4 rc][B][L][768]
  __shared__ __align__(16) char PS[49152];    // P [12][16][128] bf16 swizzled
  const int tid = threadIdx.x, lane = tid & 63, w = tid >> 6;
  const int lg = blockIdx.x, rc = blockIdx.y, b = blockIdx.z;
  const int l0 = lg * 16, r0 = rc * 128;

  // stage P slice: rows (h, lr) of 128 bf16 (256B); 12 passes x 16 rows
  {
    const int x = tid & 15, rowb = tid >> 4;
#pragma unroll
    for (int pass = 0; pass < 12; ++pass) {
      const int ri = pass * 16 + rowb;        // 0..191
      const int h = ri >> 4, lr = ri & 15;
      const char* src = (const char*)pbf +
          ((((size_t)b * 12 + h) * 512 + l0 + lr) * 512 + r0) * 2 + (size_t)x * 16;
      u32x4 v = *(const u32x4*)src;
      *(u32x4*)(PS + h * 4096 + lr * 256 + ((x * 16) ^ ((lr & 3) << 4))) = v;
    }
  }
  __syncthreads();

  const int lr_w = w * 4 + (lane >> 4);       // local l, 0..15
  const int l = l0 + lr_w;
  const char* rvb = (const char*)relv +
      (((size_t)b * 512 + r0) * 512 + l) * 256 + (size_t)(lane & 15) * 16;

  f32x4 vA[8], vB[8];
  f32x4 acc[12];
#pragma unroll
  for (int h = 0; h < 12; ++h) acc[h] = {0.f, 0.f, 0.f, 0.f};

#define VISSUE(o, buf)                                                        \
  do {                                                                        \
    GL16(buf[0], rvb + (size_t)((o) * 8 + 0) * 131072, 0);                    \
    GL16(buf[1], rvb + (size_t)((o) * 8 + 1) * 131072, 0);                    \
    GL16(buf[2], rvb + (size_t)((o) * 8 + 2) * 131072, 0);                    \
    GL16(buf[3], rvb + (size_t)((o) * 8 + 3) * 131072, 0);                    \
    GL16(buf[4], rvb + (size_t)((o) * 8 + 4) * 131072, 0);                    \
    GL16(buf[5], rvb + (size_t)((o) * 8 + 5) * 131072, 0);                    \
    GL16(buf[6], rvb + (size_t)((o) * 8 + 6) * 131072, 0);                    \
    GL16(buf[7], rvb + (size_t)((o) * 8 + 7) * 131072, 0);                    \
  } while (0)
#define VCONS(o, buf)                                                         \
  do {                                                                        \
    _Pragma("unroll")                                                         \
    for (int h = 0; h < 12; ++h) {                                            \
      bf16x8 p8 = *(const bf16x8*)(PS + h * 4096 + lr_w * 256 +               \
                                   (((o) * 16) ^ ((lr_w & 3) << 4)));         \
      _Pragma("unroll")                                                       \
      for (int j = 0; j < 8; ++j) {                                           \
        const float pf = bf2f((unsigned short)p8[j]);                         \
        acc[h] += pf * buf[j];                                                \
      }                                                                       \
    }                                                                         \
  } while (0)

  VISSUE(0, vA);
  VISSUE(1, vB);
  WAITV(8); VCONS(0, vA); VISSUE(2, vA);
  WAITV(8); VCONS(1, vB); VISSUE(3, vB);
  WAITV(8); VCONS(2, vA); VISSUE(4, vA);
  WAITV(8); VCONS(3, vB); VISSUE(5, vB);
  WAITV(8); VCONS(4, vA); VISSUE(6, vA);
  WAITV(8); VCONS(5, vB); VISSUE(7, vB);
  WAITV(8); VCONS(6, vA); VISSUE(8, vA);
  WAITV(8); VCONS(7, vB); VISSUE(9, vB);
  WAITV(8); VCONS(8, vA); VISSUE(10, vA);
  WAITV(8); VCONS(9, vB); VISSUE(11, vB);
  WAITV(8); VCONS(10, vA); VISSUE(12, vA);
  WAITV(8); VCONS(11, vB); VISSUE(13, vB);
  WAITV(8); VCONS(12, vA); VISSUE(14, vA);
  WAITV(8); VCONS(13, vB); VISSUE(15, vB);
  WAITV(8); VCONS(14, vA);
  WAITV(0); VCONS(15, vB);
#undef VISSUE
#undef VCONS

  // write partial: [rc][b][l][h*64 + dq*4 .. +3]
  float* op = part + ((size_t)rc * 2048 + (size_t)b * 512 + l) * 768 + (lane & 15) * 4;
#pragma unroll
  for (int h = 0; h < 12; ++h)
    *(f32x4*)(op + h * 64) = acc[h];
}

// ---------------- K3: ctx = P@V per (b,h) via MFMA, + 4 partials ----------
__global__ __launch_bounds__(256) void k_pv(
    const unsigned short* __restrict__ pbf, const unsigned short* __restrict__ vbt,
    const float* __restrict__ part, float* __restrict__ out) {
  __shared__ __align__(16) unsigned short lP[64 * 64];
  __shared__ __align__(16) unsigned short lV[64 * 64];
  const int tid = threadIdx.x, lane = tid & 63, w = tid >> 6;
  const int lt = blockIdx.x, bh = blockIdx.y;
  const int b = bh / 12, h = bh % 12;
  const int wm = (w >> 1) * 32, wn = (w & 1) * 32;
  f32x4 acc[2][2] = {};
  const char* pbase = (const char*)pbf + ((size_t)bh * 512 + lt * 64) * 1024;
  const char* vbase = (const char*)vbt + (size_t)bh * 64 * 1024;
  for (int kt = 0; kt < 8; ++kt) {
    __syncthreads();
#pragma unroll
    for (int i = 0; i < 2; ++i) {
      int e16 = i * 256 + tid;
      int row = e16 >> 3;
      int kb = (e16 & 7) * 16;
      int dst = row * 128 + (kb ^ ((row & 7) << 4));
      u32x4 vp = *(const u32x4*)(pbase + (size_t)row * 1024 + kt * 128 + kb);
      *(u32x4*)((char*)lP + dst) = vp;
      u32x4 vv = *(const u32x4*)(vbase + (size_t)row * 1024 + kt * 128 + kb);
      *(u32x4*)((char*)lV + dst) = vv;
    }
    __syncthreads();
#pragma unroll
    for (int ks = 0; ks < 2; ++ks) {
      bf16x8 fa[2], fb[2];
      const int kbyte = (ks * 32 + (lane >> 4) * 8) * 2;
#pragma unroll
      for (int mi = 0; mi < 2; ++mi) {
        int row = wm + mi * 16 + (lane & 15);
        fa[mi] = *(const bf16x8*)((const char*)lP + row * 128 + (kbyte ^ ((row & 7) << 4)));
      }
#pragma unroll
      for (int ni = 0; ni < 2; ++ni) {
        int row = wn + ni * 16 + (lane & 15);
        fb[ni] = *(const bf16x8*)((const char*)lV + row * 128 + (kbyte ^ ((row & 7) << 4)));
      }
#pragma unroll
      for (int mi = 0; mi < 2; ++mi)
#pragma unroll
        for (int ni = 0; ni < 2; ++ni)
          acc[mi][ni] = __builtin_amdgcn_mfma_f32_16x16x32_bf16(fa[mi], fb[ni], acc[mi][ni], 0, 0, 0);
    }
  }
#pragma unroll
  for (int mi = 0; mi < 2; ++mi)
#pragma unroll
    for (int ni = 0; ni < 2; ++ni) {
      int gd = wn + ni * 16 + (lane & 15);
#pragma unroll
      for (int r = 0; r < 4; ++r) {
        int gl = lt * 64 + wm + mi * 16 + ((lane >> 4) << 2) + r;
        size_t o = ((size_t)b * 512 + gl) * 768 + h * 64 + gd;
        out[o] = acc[mi][ni][r] + part[o] + part[o + 1572864] +
                 part[o + 2 * 1572864] + part[o + 3 * 1572864];
      }
    }
}

extern "C" void kernel_launch(void* const* d_in, const int* in_sizes, int n_in,
                              void* d_out, int out_size, void* d_ws, size_t ws_size,
                              hipStream_t stream) {
  (void)in_sizes; (void)n_in; (void)out_size; (void)ws_size;
  const float* hidden = (const float*)d_in[0];
  const float* relk   = (const float*)d_in[1];
  const float* relv   = (const float*)d_in[2];
  const float* Wq     = (const float*)d_in[3];
  const float* bq     = (const float*)d_in[4];
  const float* Wk     = (const float*)d_in[5];
  const float* bk     = (const float*)d_in[6];
  const float* Wv     = (const float*)d_in[7];
  const float* bv     = (const float*)d_in[8];
  float* out = (float*)d_out;
  char* ws = (char*)d_ws;

  unsigned short* hb  = (unsigned short*)(ws);
  unsigned short* wt  = (unsigned short*)(ws + 3145728);
  unsigned short* qbf = (unsigned short*)(ws + 6684672);
  unsigned short* kbf = (unsigned short*)(ws + 9830400);
  unsigned short* vbt = (unsigned short*)(ws + 12976128);
  float*          S   = (float*)(ws + 16121856);   // 50.3 MB, dead after k_relA
  float*          part= (float*)(ws + 16121856);   // 25.2 MB overlay (post-k_relA)
  unsigned short* pbf = (unsigned short*)(ws + 66453504);

  k_cvt_hidden<<<1536, 256, 0, stream>>>(hidden, hb);
  k_transp_w<<<dim3(12, 12, 3), 256, 0, stream>>>(Wq, Wk, Wv, wt);
  k_qkv_gemm<<<dim3(32, 36), 256, 0, stream>>>(hb, wt, bq, bk, bv, qbf, kbf, vbt);
  k_scores<<<dim3(8, 8, 48), 256, 0, stream>>>(qbf, kbf, S);
  k_relA<<<2048, 256, 0, stream>>>(qbf, relk, S, pbf);
  k_relv<<<dim3(32, 4, 4), 256, 0, stream>>>(pbf, relv, part);
  k_pv<<<dim3(8, 48), 256, 0, stream>>>(pbf, vbt, part, out);
}

// Round 8
// 186.417 us; speedup vs baseline: 1.0541x; 1.0541x over previous
//
#include <hip/hip_runtime.h>
#include <stdint.h>

// BertSelfAttentionWithRelation  B=4 L=512 H=12 D=64 HIDDEN=768
// Round 8: traffic cuts + deeper pipelines on the R7 structure.
//   S content scores stored bf16 (-50 MB), relv partials stored bf16 (-37 MB)
//   k_relA: 3-slot counted-vmcnt relk pipeline (12 loads in flight)
//   k_relv: 3-batch counted-vmcnt relv pipeline (24 loads in flight)
//   ws: hb 0 | wt 3.1M | qbf 6.7M | kbf 9.8M | vbt 13.0M | Sb/part 16.1M |
//       pbf 66.5M

typedef __attribute__((ext_vector_type(8))) short bf16x8;
typedef __attribute__((ext_vector_type(4))) float f32x4;
typedef __attribute__((ext_vector_type(4))) unsigned int u32x4;
typedef __attribute__((ext_vector_type(2))) unsigned int u32x2;

__device__ __forceinline__ unsigned short f2bf(float f) {
  union { float f; unsigned int u; } v; v.f = f;
  unsigned int r = v.u + 0x7fffu + ((v.u >> 16) & 1u);
  return (unsigned short)(r >> 16);
}
__device__ __forceinline__ float bf2f(unsigned short s) {
  union { unsigned int u; float f; } v; v.u = ((unsigned int)s) << 16;
  return v.f;
}
__device__ __forceinline__ void lds_barrier() {
  asm volatile("s_waitcnt lgkmcnt(0)\ns_barrier" ::: "memory");
}
__device__ __forceinline__ unsigned cvtpk(float lo, float hi) {
  unsigned r;
  asm("v_cvt_pk_bf16_f32 %0, %1, %2" : "=v"(r) : "v"(lo), "v"(hi));
  return r;
}

#define GL16(dst, addr, OFF)                                                  \
  asm volatile("global_load_dwordx4 %0, %1, off offset:" #OFF                \
               : "=v"(dst) : "v"(addr))
#define WAITV(N)                                                              \
  do {                                                                        \
    asm volatile("s_waitcnt vmcnt(" #N ")" ::: "memory");                     \
    __builtin_amdgcn_sched_barrier(0);                                        \
  } while (0)

// ---------------- K0a: hidden fp32 -> bf16 ----------------
__global__ void k_cvt_hidden(const float* __restrict__ x, unsigned short* __restrict__ y) {
  int i = blockIdx.x * 256 + threadIdx.x;
  float4 v = reinterpret_cast<const float4*>(x)[i];
  ushort4 o;
  o.x = f2bf(v.x); o.y = f2bf(v.y); o.z = f2bf(v.z); o.w = f2bf(v.w);
  reinterpret_cast<ushort4*>(y)[i] = o;
}

// ---------------- K0b: W -> W^T concat bf16 ----------------
__global__ void k_transp_w(const float* __restrict__ Wq, const float* __restrict__ Wk,
                           const float* __restrict__ Wv, unsigned short* __restrict__ wt) {
  __shared__ float t[64][65];
  const int kt = blockIdx.x, nt = blockIdx.y, wsel = blockIdx.z;
  const float* W = wsel == 0 ? Wq : (wsel == 1 ? Wk : Wv);
  const int lx = threadIdx.x & 63, ly = threadIdx.x >> 6;
  for (int i = 0; i < 64; i += 4)
    t[ly + i][lx] = W[(size_t)(kt * 64 + ly + i) * 768 + nt * 64 + lx];
  __syncthreads();
  for (int i = 0; i < 64; i += 4) {
    int r = ly + i;
    wt[((size_t)wsel * 768 + nt * 64 + r) * 768 + kt * 64 + lx] = f2bf(t[lx][r]);
  }
}

// ---------------- K1: fused QKV GEMM (bf16 MFMA) ----------------
__global__ __launch_bounds__(256) void k_qkv_gemm(
    const unsigned short* __restrict__ A, const unsigned short* __restrict__ Bt,
    const float* __restrict__ bq, const float* __restrict__ bk, const float* __restrict__ bv,
    unsigned short* __restrict__ qbf, unsigned short* __restrict__ kbf,
    unsigned short* __restrict__ vbt) {
  __shared__ __align__(16) unsigned short lA[64 * 64];
  __shared__ __align__(16) unsigned short lB[64 * 64];
  const int tid = threadIdx.x, lane = tid & 63, w = tid >> 6;
  const int m0 = blockIdx.x * 64, n0 = blockIdx.y * 64;
  const int wm = (w >> 1) * 32, wn = (w & 1) * 32;
  f32x4 acc[2][2] = {};

  for (int kt = 0; kt < 12; ++kt) {
    __syncthreads();
#pragma unroll
    for (int i = 0; i < 2; ++i) {
      int e16 = i * 256 + tid;
      int row = e16 >> 3;
      int kb = (e16 & 7) * 16;
      int dst = row * 128 + (kb ^ ((row & 7) << 4));
      u32x4 va = *(const u32x4*)((const char*)A + (size_t)(m0 + row) * 1536 + kt * 128 + kb);
      *(u32x4*)((char*)lA + dst) = va;
      u32x4 vb = *(const u32x4*)((const char*)Bt + (size_t)(n0 + row) * 1536 + kt * 128 + kb);
      *(u32x4*)((char*)lB + dst) = vb;
    }
    __syncthreads();
#pragma unroll
    for (int ks = 0; ks < 2; ++ks) {
      bf16x8 fa[2], fb[2];
      const int kbyte = (ks * 32 + (lane >> 4) * 8) * 2;
#pragma unroll
      for (int mi = 0; mi < 2; ++mi) {
        int row = wm + mi * 16 + (lane & 15);
        fa[mi] = *(const bf16x8*)((const char*)lA + row * 128 + (kbyte ^ ((row & 7) << 4)));
      }
#pragma unroll
      for (int ni = 0; ni < 2; ++ni) {
        int row = wn + ni * 16 + (lane & 15);
        fb[ni] = *(const bf16x8*)((const char*)lB + row * 128 + (kbyte ^ ((row & 7) << 4)));
      }
#pragma unroll
      for (int mi = 0; mi < 2; ++mi)
#pragma unroll
        for (int ni = 0; ni < 2; ++ni)
          acc[mi][ni] = __builtin_amdgcn_mfma_f32_16x16x32_bf16(fa[mi], fb[ni], acc[mi][ni], 0, 0, 0);
    }
  }
#pragma unroll
  for (int mi = 0; mi < 2; ++mi)
#pragma unroll
    for (int ni = 0; ni < 2; ++ni) {
      int gn = n0 + wn + ni * 16 + (lane & 15);
      float bias = (gn < 768) ? bq[gn] : (gn < 1536 ? bk[gn - 768] : bv[gn - 1536]);
#pragma unroll
      for (int r = 0; r < 4; ++r) {
        int gm = m0 + wm + mi * 16 + ((lane >> 4) << 2) + r;
        float val = acc[mi][ni][r] + bias;
        int b = gm >> 9, l = gm & 511;
        int d = gn & 63;
        if (gn < 768) {
          int h = gn >> 6;
          qbf[(((size_t)(b * 12 + h)) * 512 + l) * 64 + d] = f2bf(val);
        } else if (gn < 1536) {
          int h = (gn - 768) >> 6;
          kbf[(((size_t)(b * 12 + h)) * 512 + l) * 64 + d] = f2bf(val);
        } else {
          int h = (gn - 1536) >> 6;
          vbt[(((size_t)(b * 12 + h)) * 64 + d) * 512 + l] = f2bf(val);
        }
      }
    }
}

// ---------------- K2a: content scores S = q.k^T per (b,h), bf16 out -------
__global__ __launch_bounds__(256) void k_scores(
    const unsigned short* __restrict__ qbf, const unsigned short* __restrict__ kbf,
    unsigned short* __restrict__ Sb) {
  __shared__ __align__(16) unsigned short lQ[64 * 64];
  __shared__ __align__(16) unsigned short lK[64 * 64];
  const int tid = threadIdx.x, lane = tid & 63, w = tid >> 6;
  const int mt = blockIdx.x, lt = blockIdx.y, bh = blockIdx.z;
  const int wm = (w >> 1) * 32, wn = (w & 1) * 32;
  f32x4 acc[2][2] = {};
#pragma unroll
  for (int i = 0; i < 2; ++i) {
    int e16 = i * 256 + tid;
    int row = e16 >> 3;
    int kb = (e16 & 7) * 16;
    int dst = row * 128 + (kb ^ ((row & 7) << 4));
    u32x4 vq = *(const u32x4*)((const char*)qbf + ((size_t)bh * 512 + lt * 64 + row) * 128 + kb);
    *(u32x4*)((char*)lQ + dst) = vq;
    u32x4 vk = *(const u32x4*)((const char*)kbf + ((size_t)bh * 512 + mt * 64 + row) * 128 + kb);
    *(u32x4*)((char*)lK + dst) = vk;
  }
  __syncthreads();
#pragma unroll
  for (int ks = 0; ks < 2; ++ks) {
    bf16x8 fa[2], fb[2];
    const int kbyte = (ks * 32 + (lane >> 4) * 8) * 2;
#pragma unroll
    for (int mi = 0; mi < 2; ++mi) {
      int row = wm + mi * 16 + (lane & 15);
      fa[mi] = *(const bf16x8*)((const char*)lQ + row * 128 + (kbyte ^ ((row & 7) << 4)));
    }
#pragma unroll
    for (int ni = 0; ni < 2; ++ni) {
      int row = wn + ni * 16 + (lane & 15);
      fb[ni] = *(const bf16x8*)((const char*)lK + row * 128 + (kbyte ^ ((row & 7) << 4)));
    }
#pragma unroll
    for (int mi = 0; mi < 2; ++mi)
#pragma unroll
      for (int ni = 0; ni < 2; ++ni)
        acc[mi][ni] = __builtin_amdgcn_mfma_f32_16x16x32_bf16(fa[mi], fb[ni], acc[mi][ni], 0, 0, 0);
  }
#pragma unroll
  for (int mi = 0; mi < 2; ++mi)
#pragma unroll
    for (int ni = 0; ni < 2; ++ni) {
      int gm = mt * 64 + wn + ni * 16 + (lane & 15);
#pragma unroll
      for (int r = 0; r < 4; ++r) {
        int gl = lt * 64 + wm + mi * 16 + ((lane >> 4) << 2) + r;
        Sb[(size_t)bh * 262144 + (size_t)gl * 512 + gm] = f2bf(acc[mi][ni][r]);
      }
    }
}

// ---------------- K2b: rel-K scores + softmax -> pbf, one block per (b,l) --
__global__ __launch_bounds__(256, 4) void k_relA(
    const unsigned short* __restrict__ qbf,
    const float* __restrict__ relk,   // [B][L][L][D]  (b, l, r, d)
    const unsigned short* __restrict__ Sb,
    unsigned short* __restrict__ pbf) {
  __shared__ __align__(16) char X[24576];   // S_rel [12][512] f32 swizzled
  const int tid = threadIdx.x, lane = tid & 63, w = tid >> 6;
  const int bl = blockIdx.x, b = bl >> 9, l = bl & 511;
  const int lm = lane & 15, lg = lane >> 4;
  const int hq = lm < 12 ? lm : 11;

  union { f32x4 f; bf16x8 b; } qa0, qa1;
  const char* aQ = (const char*)qbf + (((size_t)b * 12 + hq) * 512 + l) * 128 + (size_t)lg * 16;
  GL16(qa0.f, aQ, 0);
  GL16(qa1.f, aQ, 64);

  const char* aA = (const char*)relk + (size_t)bl * 131072 +
                   (size_t)(w * 128 + lm) * 256 + (size_t)lg * 32;
  f32x4 td[3][4];
#define TISSUE(t, s)                                                          \
  do {                                                                        \
    const char* p_ = aA + (size_t)(t) * 4096;                                 \
    GL16(td[s][0], p_, 0);   GL16(td[s][1], p_, 16);                          \
    GL16(td[s][2], p_, 128); GL16(td[s][3], p_, 144);                         \
  } while (0)
#define ACONSUME(t, s)                                                        \
  do {                                                                        \
    union { bf16x8 v; unsigned u[4]; } fb0, fb1;                              \
    fb0.u[0] = cvtpk(td[s][0][0], td[s][0][1]);                               \
    fb0.u[1] = cvtpk(td[s][0][2], td[s][0][3]);                               \
    fb0.u[2] = cvtpk(td[s][1][0], td[s][1][1]);                               \
    fb0.u[3] = cvtpk(td[s][1][2], td[s][1][3]);                               \
    fb1.u[0] = cvtpk(td[s][2][0], td[s][2][1]);                               \
    fb1.u[1] = cvtpk(td[s][2][2], td[s][2][3]);                               \
    fb1.u[2] = cvtpk(td[s][3][0], td[s][3][1]);                               \
    fb1.u[3] = cvtpk(td[s][3][2], td[s][3][3]);                               \
    f32x4 acc = {0.f, 0.f, 0.f, 0.f};                                         \
    acc = __builtin_amdgcn_mfma_f32_16x16x32_bf16(qa0.b, fb0.v, acc, 0, 0, 0);\
    acc = __builtin_amdgcn_mfma_f32_16x16x32_bf16(qa1.b, fb1.v, acc, 0, 0, 0);\
    if (lg < 3) {                                                             \
      const int r_ = w * 128 + (t) * 16 + lm;                                 \
      _Pragma("unroll")                                                       \
      for (int reg = 0; reg < 4; ++reg)                                       \
        *(float*)(X + (lg * 4 + reg) * 2048 + ((r_ * 4) ^ (lg << 6))) =       \
            acc[reg];                                                         \
    }                                                                         \
  } while (0)

  TISSUE(0, 0); TISSUE(1, 1); TISSUE(2, 2);
  WAITV(8); ACONSUME(0, 0); TISSUE(3, 0);
  WAITV(8); ACONSUME(1, 1); TISSUE(4, 1);
  WAITV(8); ACONSUME(2, 2); TISSUE(5, 2);
  WAITV(8); ACONSUME(3, 0); TISSUE(6, 0);
  WAITV(8); ACONSUME(4, 1); TISSUE(7, 1);
  WAITV(8); ACONSUME(5, 2);
  WAITV(4); ACONSUME(6, 0);
  WAITV(0); ACONSUME(7, 1);
#undef TISSUE
#undef ACONSUME

  lds_barrier();   // S_rel visible

  // softmax; wave owns h = 3w..3w+2; content Sb (bf16) loaded inline
#pragma unroll
  for (int hh = 0; hh < 3; ++hh) {
    const int h = w * 3 + hh;
    const int sw = ((h >> 2) & 3) << 6;
    const size_t srow = (((size_t)b * 12 + h) * 512 + l) * 512;
    const unsigned short* sp = Sb + srow + lane;
    float sv[8];
    float mx = -1e30f;
#pragma unroll
    for (int j = 0; j < 8; ++j) {
      const int r = j * 64 + lane;
      float s = (*(const float*)(X + h * 2048 + ((r * 4) ^ sw)) + bf2f(sp[j * 64])) * 0.125f;
      sv[j] = s;
      mx = fmaxf(mx, s);
    }
#pragma unroll
    for (int off = 32; off; off >>= 1) mx = fmaxf(mx, __shfl_xor(mx, off));
    float sm = 0.f;
#pragma unroll
    for (int j = 0; j < 8; ++j) { sv[j] = __expf(sv[j] - mx); sm += sv[j]; }
#pragma unroll
    for (int off = 32; off; off >>= 1) sm += __shfl_xor(sm, off);
    const float inv = 1.f / sm;
#pragma unroll
    for (int j = 0; j < 8; ++j)
      pbf[srow + j * 64 + lane] = f2bf(sv[j] * inv);
  }
}

// ---------------- K2c: rel-V context, contiguous streaming ----------------
// block = (lg, rc, b): r in [rc*128, +128), l in [lg*16, +16)
// wave owns 4 l's; lane: l = l0 + w*4 + (lane>>4), d-quad = (lane&15)*4
__global__ __launch_bounds__(256, 2) void k_relv(
    const unsigned short* __restrict__ pbf,   // [B][H][L][R] bf16
    const float* __restrict__ relv,           // [B][R][L][D] f32
    unsigned short* __restrict__ part) {      // [4 rc][B][L][768] bf16
  __shared__ __align__(16) char PS[49152];    // P [12][16][128] bf16 swizzled
  const int tid = threadIdx.x, lane = tid & 63, w = tid >> 6;
  const int lg = blockIdx.x, rc = blockIdx.y, b = blockIdx.z;
  const int l0 = lg * 16, r0 = rc * 128;

  // stage P slice: rows (h, lr) of 128 bf16 (256B); 12 passes x 16 rows
  {
    const int x = tid & 15, rowb = tid >> 4;
#pragma unroll
    for (int pass = 0; pass < 12; ++pass) {
      const int ri = pass * 16 + rowb;        // 0..191
      const int h = ri >> 4, lr = ri & 15;
      const char* src = (const char*)pbf +
          ((((size_t)b * 12 + h) * 512 + l0 + lr) * 512 + r0) * 2 + (size_t)x * 16;
      u32x4 v = *(const u32x4*)src;
      *(u32x4*)(PS + h * 4096 + lr * 256 + ((x * 16) ^ ((lr & 3) << 4))) = v;
    }
  }
  __syncthreads();

  const int lr_w = w * 4 + (lane >> 4);       // local l, 0..15
  const int l = l0 + lr_w;
  const char* rvb = (const char*)relv +
      (((size_t)b * 512 + r0) * 512 + l) * 256 + (size_t)(lane & 15) * 16;

  f32x4 vA[8], vB[8], vC[8];
  f32x4 acc[12];
#pragma unroll
  for (int h = 0; h < 12; ++h) acc[h] = {0.f, 0.f, 0.f, 0.f};

#define VISSUE(o, buf)                                                        \
  do {                                                                        \
    GL16(buf[0], rvb + (size_t)((o) * 8 + 0) * 131072, 0);                    \
    GL16(buf[1], rvb + (size_t)((o) * 8 + 1) * 131072, 0);                    \
    GL16(buf[2], rvb + (size_t)((o) * 8 + 2) * 131072, 0);                    \
    GL16(buf[3], rvb + (size_t)((o) * 8 + 3) * 131072, 0);                    \
    GL16(buf[4], rvb + (size_t)((o) * 8 + 4) * 131072, 0);                    \
    GL16(buf[5], rvb + (size_t)((o) * 8 + 5) * 131072, 0);                    \
    GL16(buf[6], rvb + (size_t)((o) * 8 + 6) * 131072, 0);                    \
    GL16(buf[7], rvb + (size_t)((o) * 8 + 7) * 131072, 0);                    \
  } while (0)
#define VCONS(o, buf)                                                         \
  do {                                                                        \
    _Pragma("unroll")                                                         \
    for (int h = 0; h < 12; ++h) {                                            \
      bf16x8 p8 = *(const bf16x8*)(PS + h * 4096 + lr_w * 256 +               \
                                   (((o) * 16) ^ ((lr_w & 3) << 4)));         \
      _Pragma("unroll")                                                       \
      for (int j = 0; j < 8; ++j) {                                           \
        const float pf = bf2f((unsigned short)p8[j]);                         \
        acc[h] += pf * buf[j];                                                \
      }                                                                       \
    }                                                                         \
  } while (0)

  VISSUE(0, vA);
  VISSUE(1, vB);
  VISSUE(2, vC);
  WAITV(16); VCONS(0, vA);  VISSUE(3, vA);
  WAITV(16); VCONS(1, vB);  VISSUE(4, vB);
  WAITV(16); VCONS(2, vC);  VISSUE(5, vC);
  WAITV(16); VCONS(3, vA);  VISSUE(6, vA);
  WAITV(16); VCONS(4, vB);  VISSUE(7, vB);
  WAITV(16); VCONS(5, vC);  VISSUE(8, vC);
  WAITV(16); VCONS(6, vA);  VISSUE(9, vA);
  WAITV(16); VCONS(7, vB);  VISSUE(10, vB);
  WAITV(16); VCONS(8, vC);  VISSUE(11, vC);
  WAITV(16); VCONS(9, vA);  VISSUE(12, vA);
  WAITV(16); VCONS(10, vB); VISSUE(13, vB);
  WAITV(16); VCONS(11, vC); VISSUE(14, vC);
  WAITV(16); VCONS(12, vA); VISSUE(15, vA);
  WAITV(16); VCONS(13, vB);
  WAITV(8);  VCONS(14, vC);
  WAITV(0);  VCONS(15, vA);
#undef VISSUE
#undef VCONS

  // write partial bf16: [rc][b][l][h*64 + dq*4 .. +3]
  unsigned short* op = part + ((size_t)rc * 2048 + (size_t)b * 512 + l) * 768 + (lane & 15) * 4;
#pragma unroll
  for (int h = 0; h < 12; ++h) {
    u32x2 pk;
    pk.x = cvtpk(acc[h][0], acc[h][1]);
    pk.y = cvtpk(acc[h][2], acc[h][3]);
    *(u32x2*)(op + h * 64) = pk;
  }
}

// ---------------- K3: ctx = P@V per (b,h) via MFMA, + 4 bf16 partials -----
__global__ __launch_bounds__(256) void k_pv(
    const unsigned short* __restrict__ pbf, const unsigned short* __restrict__ vbt,
    const unsigned short* __restrict__ part, float* __restrict__ out) {
  __shared__ __align__(16) unsigned short lP[64 * 64];
  __shared__ __align__(16) unsigned short lV[64 * 64];
  const int tid = threadIdx.x, lane = tid & 63, w = tid >> 6;
  const int lt = blockIdx.x, bh = blockIdx.y;
  const int b = bh / 12, h = bh % 12;
  const int wm = (w >> 1) * 32, wn = (w & 1) * 32;
  f32x4 acc[2][2] = {};
  const char* pbase = (const char*)pbf + ((size_t)bh * 512 + lt * 64) * 1024;
  const char* vbase = (const char*)vbt + (size_t)bh * 64 * 1024;
  for (int kt = 0; kt < 8; ++kt) {
    __syncthreads();
#pragma unroll
    for (int i = 0; i < 2; ++i) {
      int e16 = i * 256 + tid;
      int row = e16 >> 3;
      int kb = (e16 & 7) * 16;
      int dst = row * 128 + (kb ^ ((row & 7) << 4));
      u32x4 vp = *(const u32x4*)(pbase + (size_t)row * 1024 + kt * 128 + kb);
      *(u32x4*)((char*)lP + dst) = vp;
      u32x4 vv = *(const u32x4*)(vbase + (size_t)row * 1024 + kt * 128 + kb);
      *(u32x4*)((char*)lV + dst) = vv;
    }
    __syncthreads();
#pragma unroll
    for (int ks = 0; ks < 2; ++ks) {
      bf16x8 fa[2], fb[2];
      const int kbyte = (ks * 32 + (lane >> 4) * 8) * 2;
#pragma unroll
      for (int mi = 0; mi < 2; ++mi) {
        int row = wm + mi * 16 + (lane & 15);
        fa[mi] = *(const bf16x8*)((const char*)lP + row * 128 + (kbyte ^ ((row & 7) << 4)));
      }
#pragma unroll
      for (int ni = 0; ni < 2; ++ni) {
        int row = wn + ni * 16 + (lane & 15);
        fb[ni] = *(const bf16x8*)((const char*)lV + row * 128 + (kbyte ^ ((row & 7) << 4)));
      }
#pragma unroll
      for (int mi = 0; mi < 2; ++mi)
#pragma unroll
        for (int ni = 0; ni < 2; ++ni)
          acc[mi][ni] = __builtin_amdgcn_mfma_f32_16x16x32_bf16(fa[mi], fb[ni], acc[mi][ni], 0, 0, 0);
    }
  }
#pragma unroll
  for (int mi = 0; mi < 2; ++mi)
#pragma unroll
    for (int ni = 0; ni < 2; ++ni) {
      int gd = wn + ni * 16 + (lane & 15);
#pragma unroll
      for (int r = 0; r < 4; ++r) {
        int gl = lt * 64 + wm + mi * 16 + ((lane >> 4) << 2) + r;
        size_t o = ((size_t)b * 512 + gl) * 768 + h * 64 + gd;
        out[o] = acc[mi][ni][r] + bf2f(part[o]) + bf2f(part[o + 1572864]) +
                 bf2f(part[o + 3145728]) + bf2f(part[o + 4718592]);
      }
    }
}

extern "C" void kernel_launch(void* const* d_in, const int* in_sizes, int n_in,
                              void* d_out, int out_size, void* d_ws, size_t ws_size,
                              hipStream_t stream) {
  (void)in_sizes; (void)n_in; (void)out_size; (void)ws_size;
  const float* hidden = (const float*)d_in[0];
  const float* relk   = (const float*)d_in[1];
  const float* relv   = (const float*)d_in[2];
  const float* Wq     = (const float*)d_in[3];
  const float* bq     = (const float*)d_in[4];
  const float* Wk     = (const float*)d_in[5];
  const float* bk     = (const float*)d_in[6];
  const float* Wv     = (const float*)d_in[7];
  const float* bv     = (const float*)d_in[8];
  float* out = (float*)d_out;
  char* ws = (char*)d_ws;

  unsigned short* hb  = (unsigned short*)(ws);
  unsigned short* wt  = (unsigned short*)(ws + 3145728);
  unsigned short* qbf = (unsigned short*)(ws + 6684672);
  unsigned short* kbf = (unsigned short*)(ws + 9830400);
  unsigned short* vbt = (unsigned short*)(ws + 12976128);
  unsigned short* Sb  = (unsigned short*)(ws + 16121856);  // 25.2 MB, dead after k_relA
  unsigned short* part= (unsigned short*)(ws + 16121856);  // 12.6 MB overlay (post-k_relA)
  unsigned short* pbf = (unsigned short*)(ws + 66453504);

  k_cvt_hidden<<<1536, 256, 0, stream>>>(hidden, hb);
  k_transp_w<<<dim3(12, 12, 3), 256, 0, stream>>>(Wq, Wk, Wv, wt);
  k_qkv_gemm<<<dim3(32, 36), 256, 0, stream>>>(hb, wt, bq, bk, bv, qbf, kbf, vbt);
  k_scores<<<dim3(8, 8, 48), 256, 0, stream>>>(qbf, kbf, Sb);
  k_relA<<<2048, 256, 0, stream>>>(qbf, relk, Sb, pbf);
  k_relv<<<dim3(32, 4, 4), 256, 0, stream>>>(pbf, relv, part);
  k_pv<<<dim3(8, 48), 256, 0, stream>>>(pbf, vbt, part, out);
}